// Round 9
// baseline (310.553 us; speedup 1.0000x reference)
//
#include <hip/hip_runtime.h>
#include <hip/hip_bf16.h>

#define B_ 2
#define L_ 4096
#define D_ 1024
#define H_ 16
#define DK_ 64
#define R_ (B_*L_)   // 8192 tokens
#define N3_ 3072     // fused QKV width

typedef __bf16 bf16x8 __attribute__((ext_vector_type(8)));
typedef float  f32x4  __attribute__((ext_vector_type(4)));

__device__ __forceinline__ float bf2f(unsigned short u) {
    return __uint_as_float(((unsigned int)u) << 16);
}
__device__ __forceinline__ unsigned short f2bf(float f) {   // RNE
    unsigned int u = __float_as_uint(f);
    return (unsigned short)((u + 0x7fffu + ((u >> 16) & 1u)) >> 16);
}

// async global->LDS, 16 B per lane; LDS dest = wave-uniform base + lane*16
__device__ __forceinline__ void gl_lds16(const void* g, void* l) {
    __builtin_amdgcn_global_load_lds(
        (const __attribute__((address_space(1))) void*)(uintptr_t)g,
        (__attribute__((address_space(3))) void*)(unsigned int)(uintptr_t)l,
        16, 0, 0);
}

// ---------------------------------------------------------------------------
// prep_all: one kernel for all input conversions.
// ---------------------------------------------------------------------------
__global__ __launch_bounds__(256) void prep_all_kernel(
    const float* __restrict__ x,
    const float* __restrict__ Wq, const float* __restrict__ Wk,
    const float* __restrict__ Wv, const float* __restrict__ Wo,
    const float* __restrict__ Wb, const float* __restrict__ Wfd,
    const float* __restrict__ Wsd, const float* __restrict__ Wtf1,
    unsigned short* __restrict__ xb, unsigned short* __restrict__ Wtqkv,
    unsigned short* __restrict__ Wto, unsigned short* __restrict__ W3t,
    unsigned short* __restrict__ Wtf1t)
{
    __shared__ unsigned short tile[32][33];
    const int bx = blockIdx.x, t = threadIdx.x;
    if (bx < 8192) {
        const int i = bx * 256 + t;
        float4 v = ((const float4*)x)[i];
        ushort4 o;
        o.x = f2bf(v.x); o.y = f2bf(v.y); o.z = f2bf(v.z); o.w = f2bf(v.w);
        ((ushort4*)xb)[i] = o;
    } else if (bx < 8192 + 4096) {
        const int id = bx - 8192;
        const int which = id >> 10, idx = id & 1023;
        const float* W = which == 0 ? Wq : (which == 1 ? Wk : (which == 2 ? Wv : Wo));
        unsigned short* Wt = which < 3 ? Wtqkv + (size_t)which * D_ * D_ : Wto;
        const int bn = (idx & 31) * 32, bk = (idx >> 5) * 32;
        const int tx = t & 31, ty = t >> 5;
        #pragma unroll
        for (int r = ty; r < 32; r += 8)
            tile[tx][r] = f2bf(W[(size_t)(bk + r) * D_ + bn + tx]);
        __syncthreads();
        #pragma unroll
        for (int r = ty; r < 32; r += 8)
            Wt[(size_t)(bn + r) * D_ + bk + tx] = tile[r][tx];
    } else if (bx < 8192 + 4096 + 192) {
        const int i = (bx - (8192 + 4096)) * 256 + t;
        const int c = i >> 10, k = i & 1023;
        const float* W = c < 16 ? Wb : (c < 32 ? Wfd : Wsd);
        W3t[i] = f2bf(W[k * H_ + (c & 15)]);
    } else {
        for (int i = t; i < 32 * 64; i += 256) {
            const int j = i >> 6, d = i & 63;
            Wtf1t[i] = f2bf(Wtf1[d * 32 + j]);
        }
    }
}

// ---------------------------------------------------------------------------
// bf16 MFMA GEMM (m97 + XOR-swizzled LDS): C = A[M,K] @ Bt[N,K]^T.
// LDS chunk position p of row r holds global k-chunk p ^ ((r>>1)&3) ->
// frag ds_read_b128 aliasing drops from 8-way to 2-way (free).
// OUTBF: bf16 C via LDS repack (stride-132 pad); else fp32 C via LDS repack
// float4 stores. 128x128 tile, BK=32, 256 thr, 4x4 16x16 frags/wave.
// ---------------------------------------------------------------------------
template <bool OUTBF>
__global__ __launch_bounds__(256) void gemm_bf16_kernel(
    const unsigned short* __restrict__ A,   // [M,K] bf16 bits
    const unsigned short* __restrict__ Bt,  // [N,K] bf16 bits
    void* __restrict__ Cp, int M, int N, int K)
{
    __shared__ unsigned short sh[8704];     // As | Bs (16384 B) ; C repack (17408 B)
    unsigned short* As = sh;
    unsigned short* Bs = sh + 128 * 32;
    const int bm = blockIdx.y * 128;
    const int bn = blockIdx.x * 128;
    const int t = threadIdx.x;
    const int wv = t >> 6, lane = t & 63;
    const int q  = lane >> 4, ml = lane & 15;
    const int wm = (wv >> 1) * 64, wn = (wv & 1) * 64;
    const int row4 = t >> 2;
    const int kswz = (((t & 3) ^ ((row4 >> 1) & 3))) * 8;   // swizzled source chunk
    const int cread = (q ^ ((ml >> 1) & 3)) * 8;            // swizzled read chunk
    f32x4 acc[4][4] = {};
    for (int k0 = 0; k0 < K; k0 += 32) {
        __syncthreads();
        #pragma unroll
        for (int i = 0; i < 2; ++i) {
            const unsigned short* ga = A  + (size_t)(bm + i * 64 + row4) * K + k0 + kswz;
            const unsigned short* gb = Bt + (size_t)(bn + i * 64 + row4) * K + k0 + kswz;
            gl_lds16(ga, &As[(i * 256 + wv * 64) * 8]);
            gl_lds16(gb, &Bs[(i * 256 + wv * 64) * 8]);
        }
        __syncthreads();
        bf16x8 af[4], bfr[4];
        #pragma unroll
        for (int i = 0; i < 4; ++i)
            af[i] = *(const bf16x8*)&As[(wm + i * 16 + ml) * 32 + cread];
        #pragma unroll
        for (int j = 0; j < 4; ++j)
            bfr[j] = *(const bf16x8*)&Bs[(wn + j * 16 + ml) * 32 + cread];
        #pragma unroll
        for (int i = 0; i < 4; ++i)
            #pragma unroll
            for (int j = 0; j < 4; ++j)
                acc[i][j] = __builtin_amdgcn_mfma_f32_16x16x32_bf16(af[i], bfr[j], acc[i][j], 0, 0, 0);
    }
    if constexpr (OUTBF) {
        // repack through LDS (stride 132) in two 64-row chunks -> uint4 stores
        #pragma unroll
        for (int chunk = 0; chunk < 2; ++chunk) {
            __syncthreads();
            if ((wv >> 1) == chunk) {
                #pragma unroll
                for (int i = 0; i < 4; ++i)
                    #pragma unroll
                    for (int r = 0; r < 4; ++r) {
                        const int lr = i * 16 + q * 4 + r;
                        #pragma unroll
                        for (int j = 0; j < 4; ++j)
                            sh[lr * 132 + wn + j * 16 + ml] = f2bf(acc[i][j][r]);
                    }
            }
            __syncthreads();
            #pragma unroll
            for (int u = 0; u < 4; ++u) {
                const int id = t + u * 256;
                const int row = id >> 4, colc = (id & 15) * 8;
                *(uint4*)((unsigned short*)Cp + (size_t)(bm + chunk * 64 + row) * N + bn + colc)
                    = *(const uint4*)&sh[row * 132 + colc];
            }
        }
    } else {
        // fp32: repack through LDS (float stride 132) in four 32-row chunks
        float* shf = (float*)sh;
        #pragma unroll
        for (int chunk = 0; chunk < 4; ++chunk) {
            __syncthreads();
            if ((wv >> 1) == (chunk >> 1)) {
                #pragma unroll
                for (int ii = 0; ii < 2; ++ii) {
                    const int i = (chunk & 1) * 2 + ii;
                    #pragma unroll
                    for (int r = 0; r < 4; ++r) {
                        const int lr = i * 16 + q * 4 + r - (chunk & 1) * 32;
                        #pragma unroll
                        for (int j = 0; j < 4; ++j)
                            shf[lr * 132 + wn + j * 16 + ml] = acc[i][j][r];
                    }
                }
            }
            __syncthreads();
            const int row = t >> 3, colf = (t & 7) * 16;
            float* dst = (float*)Cp + (size_t)(bm + chunk * 32 + row) * N + bn + colf;
            const float* srcp = &shf[row * 132 + colf];
            #pragma unroll
            for (int u = 0; u < 4; ++u)
                *(float4*)(dst + u * 4) = *(const float4*)(srcp + u * 4);
        }
    }
}

// ---------------------------------------------------------------------------
// Small projections via MFMA: C[8192 x 48] = xb @ W3t^T; sigmoid(+bias).
// ---------------------------------------------------------------------------
__global__ __launch_bounds__(256) void proj_mfma_kernel(
    const unsigned short* __restrict__ xb, const unsigned short* __restrict__ W3t,
    const float* __restrict__ bfd, const float* __restrict__ bsd,
    float* __restrict__ beta, float* __restrict__ fastd, float* __restrict__ slowd)
{
    __shared__ unsigned short xs[64 * 32];
    __shared__ unsigned short wsh[48 * 32];
    const int t = threadIdx.x, wv = t >> 6, lane = t & 63;
    const int q = lane >> 4, ml = lane & 15;
    const int r0 = blockIdx.x * 64;
    f32x4 acc[3] = {};
    for (int k0 = 0; k0 < D_; k0 += 32) {
        __syncthreads();
        gl_lds16(xb + (size_t)(r0 + wv * 16 + (lane >> 2)) * D_ + k0 + (lane & 3) * 8,
                 &xs[wv * 512]);
        if (wv < 3)
            gl_lds16(W3t + (size_t)(wv * 16 + (lane >> 2)) * D_ + k0 + (lane & 3) * 8,
                     &wsh[wv * 512]);
        __syncthreads();
        bf16x8 af = *(const bf16x8*)&xs[(wv * 16 + ml) * 32 + q * 8];
        #pragma unroll
        for (int j = 0; j < 3; ++j) {
            bf16x8 bfr = *(const bf16x8*)&wsh[(j * 16 + ml) * 32 + q * 8];
            acc[j] = __builtin_amdgcn_mfma_f32_16x16x32_bf16(af, bfr, acc[j], 0, 0, 0);
        }
    }
    #pragma unroll
    for (int j = 0; j < 3; ++j) {
        #pragma unroll
        for (int r = 0; r < 4; ++r) {
            const int rg = r0 + wv * 16 + q * 4 + r;
            float v = acc[j][r];
            if (j == 1) v += bfd[ml];
            if (j == 2) v += bsd[ml];
            const float sg = 1.f / (1.f + expf(-v));
            const int b = rg >> 12, l = rg & (L_ - 1);
            float* dst = j == 0 ? beta : (j == 1 ? fastd : slowd);
            dst[(size_t)(b * H_ + ml) * L_ + l] = sg;
        }
    }
}

// ---------------------------------------------------------------------------
// Per-(b,h) scan of log(decay+1e-6); w = exp(total - cs); denom = sum(w)+1e-6.
// ---------------------------------------------------------------------------
__global__ __launch_bounds__(256) void scan_kernel(
    const float* __restrict__ fastd, const float* __restrict__ slowd,
    float* __restrict__ fw, float* __restrict__ sw, float* __restrict__ denom)
{
    __shared__ float part[256];
    const int bh = blockIdx.x >> 1;
    const int which = blockIdx.x & 1;
    const float* src = (which ? slowd : fastd) + (size_t)bh * L_;
    float* dst = (which ? sw : fw) + (size_t)bh * L_;
    const int t = threadIdx.x;
    float vals[16];
    float run = 0.f;
    #pragma unroll
    for (int i = 0; i < 16; ++i) {
        run += logf(src[t * 16 + i] + 1e-6f);
        vals[i] = run;
    }
    part[t] = run;
    __syncthreads();
    for (int off = 1; off < 256; off <<= 1) {
        float v = (t >= off) ? part[t - off] : 0.f;
        __syncthreads();
        part[t] += v;
        __syncthreads();
    }
    const float excl = part[t] - run;
    const float total = part[255];
    __syncthreads();
    float lsum = 0.f;
    #pragma unroll
    for (int i = 0; i < 16; ++i) {
        float w = expf(total - (vals[i] + excl));
        dst[t * 16 + i] = w;
        lsum += w;
    }
    part[t] = lsum;
    __syncthreads();
    for (int off = 128; off > 0; off >>= 1) {
        if (t < off) part[t] += part[t + off];
        __syncthreads();
    }
    if (t == 0) denom[bh * 2 + which] = part[0] + 1e-6f;
}

// ---------------------------------------------------------------------------
// ktv_flux: k-norm + beta scale -> kfT/ksT/vT; fused token-flux MLP -> alphaA.
// ---------------------------------------------------------------------------
__global__ __launch_bounds__(256) void ktv_flux_kernel(
    const unsigned short* __restrict__ QKVb,
    const float* __restrict__ beta, const float* __restrict__ fw,
    const float* __restrict__ sw,
    const unsigned short* __restrict__ Wtf1t, const float* __restrict__ btf1,
    const float* __restrict__ Wtf2, const float* __restrict__ btf2,
    unsigned short* __restrict__ kfT, unsigned short* __restrict__ ksT,
    unsigned short* __restrict__ vT, float* __restrict__ alphaA)
{
    __shared__ float kb_s[64][65];
    __shared__ float vb_s[64][65];
    __shared__ unsigned short kbt[64][72];
    __shared__ unsigned short wtf[32][72];
    __shared__ float ps[64][4];
    __shared__ float scl[64], bl[64], fws[64], sws[64];
    __shared__ float b1s[32], w2s[32];
    const int h = blockIdx.x, b = blockIdx.y, lc = blockIdx.z;
    const int l0 = lc * 64;
    const int bh = b * H_ + h;
    const int t = threadIdx.x;
    const int wv = t >> 6, lane = t & 63;
    const int q = lane >> 4, ml = lane & 15;
    const int ll = t >> 2, dq = (t & 3) * 16;
    {
        const size_t rowb = (size_t)(b * L_ + l0 + ll) * N3_ + h * DK_ + dq;
        float s = 0.f;
        #pragma unroll
        for (int u = 0; u < 2; ++u) {
            ushort4 kv = *(const ushort4*)(QKVb + rowb + 1024 + u * 4);
            ushort4 k2 = *(const ushort4*)(QKVb + rowb + 1024 + 8 + u * 4);
            ushort4 vv = *(const ushort4*)(QKVb + rowb + 2048 + u * 4);
            ushort4 v2 = *(const ushort4*)(QKVb + rowb + 2048 + 8 + u * 4);
            float k0f = bf2f(kv.x), k1f = bf2f(kv.y), k2f = bf2f(kv.z), k3f = bf2f(kv.w);
            float k4f = bf2f(k2.x), k5f = bf2f(k2.y), k6f = bf2f(k2.z), k7f = bf2f(k2.w);
            kb_s[ll][dq + u * 4 + 0] = k0f; kb_s[ll][dq + u * 4 + 1] = k1f;
            kb_s[ll][dq + u * 4 + 2] = k2f; kb_s[ll][dq + u * 4 + 3] = k3f;
            kb_s[ll][dq + 8 + u * 4 + 0] = k4f; kb_s[ll][dq + 8 + u * 4 + 1] = k5f;
            kb_s[ll][dq + 8 + u * 4 + 2] = k6f; kb_s[ll][dq + 8 + u * 4 + 3] = k7f;
            s += k0f * k0f + k1f * k1f + k2f * k2f + k3f * k3f;
            s += k4f * k4f + k5f * k5f + k6f * k6f + k7f * k7f;
            vb_s[ll][dq + u * 4 + 0] = bf2f(vv.x); vb_s[ll][dq + u * 4 + 1] = bf2f(vv.y);
            vb_s[ll][dq + u * 4 + 2] = bf2f(vv.z); vb_s[ll][dq + u * 4 + 3] = bf2f(vv.w);
            vb_s[ll][dq + 8 + u * 4 + 0] = bf2f(v2.x); vb_s[ll][dq + 8 + u * 4 + 1] = bf2f(v2.y);
            vb_s[ll][dq + 8 + u * 4 + 2] = bf2f(v2.z); vb_s[ll][dq + 8 + u * 4 + 3] = bf2f(v2.w);
        }
        ps[ll][t & 3] = s;
        if (t < 64) {
            bl[t]  = beta[(size_t)bh * L_ + l0 + t];
            fws[t] = fw[(size_t)bh * L_ + l0 + t];
            sws[t] = sw[(size_t)bh * L_ + l0 + t];
        }
        {
            const int row = t >> 3, ko = (t & 7) * 8;
            if (row < 32)
                *(uint4*)&wtf[row][ko] = *(const uint4*)(Wtf1t + row * DK_ + ko);
            if (t < 32) { b1s[t] = btf1[t]; w2s[t] = Wtf2[t]; }
        }
    }
    __syncthreads();
    if (t < 64) {
        const float n = sqrtf(ps[t][0] + ps[t][1] + ps[t][2] + ps[t][3]);
        scl[t] = bl[t] / fmaxf(n, 1e-12f);
    }
    __syncthreads();
    {
        const float s = scl[ll];
        #pragma unroll
        for (int j = 0; j < 16; ++j) kbt[ll][dq + j] = f2bf(kb_s[ll][dq + j] * s);
    }
    {
        const int d = t >> 2, lq = (t & 3) * 16;
        __align__(16) unsigned short bF[16], bS[16], bV[16];
        #pragma unroll
        for (int j = 0; j < 16; ++j) {
            const int l = lq + j;
            const float kb = kb_s[l][d] * scl[l];
            bF[j] = f2bf(kb * fws[l]);
            bS[j] = f2bf(kb * sws[l]);
            bV[j] = f2bf(vb_s[l][d] * bl[l]);
        }
        const size_t base = ((size_t)bh * DK_ + d) * L_ + l0 + lq;
        *(uint4*)(kfT + base) = *(const uint4*)&bF[0];
        *(uint4*)(kfT + base + 8) = *(const uint4*)&bF[8];
        *(uint4*)(ksT + base) = *(const uint4*)&bS[0];
        *(uint4*)(ksT + base + 8) = *(const uint4*)&bS[8];
        *(uint4*)(vT + base) = *(const uint4*)&bV[0];
        *(uint4*)(vT + base + 8) = *(const uint4*)&bV[8];
    }
    __syncthreads();
    {
        const int wm_t = wv * 16;
        f32x4 fac[2] = {};
        #pragma unroll
        for (int kk = 0; kk < 2; ++kk) {
            bf16x8 af = *(const bf16x8*)&kbt[wm_t + ml][kk * 32 + q * 8];
            #pragma unroll
            for (int n = 0; n < 2; ++n) {
                bf16x8 bf = *(const bf16x8*)&wtf[n * 16 + ml][kk * 32 + q * 8];
                fac[n] = __builtin_amdgcn_mfma_f32_16x16x32_bf16(af, bf, fac[n], 0, 0, 0);
            }
        }
        const float bt2 = btf2[0];
        #pragma unroll
        for (int r = 0; r < 4; ++r) {
            float v = 0.f;
            #pragma unroll
            for (int n = 0; n < 2; ++n) {
                const int col = n * 16 + ml;
                const float hm = fac[n][r] + b1s[col];
                v += (hm / (1.f + expf(-hm))) * w2s[col];
            }
            v += __shfl_xor(v, 1, 64);
            v += __shfl_xor(v, 2, 64);
            v += __shfl_xor(v, 4, 64);
            v += __shfl_xor(v, 8, 64);
            if (ml == 0) {
                float tf = 1.f / (1.f + expf(-(v + bt2)));
                tf = fminf(fmaxf(tf, 0.01f), 0.99f);
                alphaA[(size_t)bh * L_ + l0 + wm_t + q * 4 + r] = 0.5f + 0.3f * tf;
            }
        }
    }
}

// ---------------------------------------------------------------------------
// M_fast/M_slow via MFMA; fp32 atomicAdd epilogue.
// ---------------------------------------------------------------------------
__global__ __launch_bounds__(256) void mstate_mfma_kernel(
    const unsigned short* __restrict__ kfT, const unsigned short* __restrict__ ksT,
    const unsigned short* __restrict__ vT,
    float* __restrict__ Mf, float* __restrict__ Ms)
{
    __shared__ unsigned short kf_s[64 * 32];
    __shared__ unsigned short ks_s[64 * 32];
    __shared__ unsigned short v_s[64 * 32];
    const int bh = blockIdx.x;
    const int seg = blockIdx.y;
    const int t = threadIdx.x, wv = t >> 6, lane = t & 63;
    const int q = lane >> 4, ml = lane & 15;
    const int wm = (wv >> 1) * 32, wn = (wv & 1) * 32;
    const size_t hb = (size_t)bh * DK_ * L_;
    const size_t grow = hb + (size_t)(wv * 16 + (lane >> 2)) * L_ + (lane & 3) * 8;
    f32x4 aF[2][2] = {}, aS[2][2] = {};
    for (int l0 = seg * 256; l0 < seg * 256 + 256; l0 += 32) {
        __syncthreads();
        gl_lds16(kfT + grow + l0, &kf_s[wv * 512]);
        gl_lds16(ksT + grow + l0, &ks_s[wv * 512]);
        gl_lds16(vT  + grow + l0, &v_s[wv * 512]);
        __syncthreads();
        bf16x8 fa[2], sa[2], vb[2];
        #pragma unroll
        for (int i = 0; i < 2; ++i) {
            fa[i] = *(const bf16x8*)&kf_s[(wm + i * 16 + ml) * 32 + q * 8];
            sa[i] = *(const bf16x8*)&ks_s[(wm + i * 16 + ml) * 32 + q * 8];
            vb[i] = *(const bf16x8*)&v_s[(wn + i * 16 + ml) * 32 + q * 8];
        }
        #pragma unroll
        for (int i = 0; i < 2; ++i)
            #pragma unroll
            for (int j = 0; j < 2; ++j) {
                aF[i][j] = __builtin_amdgcn_mfma_f32_16x16x32_bf16(fa[i], vb[j], aF[i][j], 0, 0, 0);
                aS[i][j] = __builtin_amdgcn_mfma_f32_16x16x32_bf16(sa[i], vb[j], aS[i][j], 0, 0, 0);
            }
    }
    #pragma unroll
    for (int i = 0; i < 2; ++i)
        #pragma unroll
        for (int j = 0; j < 2; ++j)
            #pragma unroll
            for (int r = 0; r < 4; ++r) {
                const int d = wm + i * 16 + q * 4 + r;
                const int e = wn + j * 16 + ml;
                atomicAdd(&Mf[(size_t)bh * (DK_ * DK_) + d * DK_ + e], aF[i][j][r]);
                atomicAdd(&Ms[(size_t)bh * (DK_ * DK_) + d * DK_ + e], aS[i][j][r]);
            }
}

// ---------------------------------------------------------------------------
// MtFS[bh][128][64] bf16: rows 0-63 = (Mf/dF)^T, 64-127 = (Ms/dS)^T
// ---------------------------------------------------------------------------
__global__ __launch_bounds__(256) void mprep_kernel(
    const float* __restrict__ Mf, const float* __restrict__ Ms,
    const float* __restrict__ denom, unsigned short* __restrict__ MtFS)
{
    __shared__ float mt[64][65];
    const int bh = blockIdx.x;
    const int t = threadIdx.x;
    const int r = t >> 2, c0 = (t & 3) * 16;
    #pragma unroll
    for (int s = 0; s < 2; ++s) {
        const float* M = (s == 0 ? Mf : Ms) + (size_t)bh * (DK_ * DK_);
        const float dn = denom[bh * 2 + s];
        __syncthreads();
        #pragma unroll
        for (int u = 0; u < 4; ++u) {
            float4 v = *(const float4*)&M[r * DK_ + c0 + u * 4];
            mt[r][c0 + u * 4 + 0] = v.x; mt[r][c0 + u * 4 + 1] = v.y;
            mt[r][c0 + u * 4 + 2] = v.z; mt[r][c0 + u * 4 + 3] = v.w;
        }
        __syncthreads();
        __align__(16) unsigned short ob[16];
        #pragma unroll
        for (int j = 0; j < 16; ++j) ob[j] = f2bf(mt[c0 + j][r] / dn);
        unsigned short* dst = MtFS + ((size_t)bh * 128 + s * 64 + r) * 64 + c0;
        *(uint4*)dst = *(const uint4*)&ob[0];
        *(uint4*)(dst + 8) = *(const uint4*)&ob[8];
    }
}

// ---------------------------------------------------------------------------
// o via MFMA: 128 tokens x 64 e per block; q-norm folded in epilogue.
// ---------------------------------------------------------------------------
__global__ __launch_bounds__(256) void o_mfma_kernel(
    const unsigned short* __restrict__ QKVb, const unsigned short* __restrict__ MtFS,
    const float* __restrict__ alphaA, unsigned short* __restrict__ Ob)
{
    __shared__ unsigned short As[128 * 72];
    __shared__ unsigned short Bs[128 * 72];
    __shared__ float al[128];
    __shared__ float qs2[128][2];
    __shared__ float nrm[128];
    const int bh = blockIdx.x, lb = blockIdx.y;
    const int b = bh >> 4, h = bh & 15;
    const int t = threadIdx.x, wv = t >> 6, lane = t & 63;
    const int q = lane >> 4, ml = lane & 15;
    const int l0 = lb * 128;
    const int r0 = b * L_ + l0;
    #pragma unroll
    for (int c = 0; c < 4; ++c) {
        const int id = t + c * 256;
        const int row = id >> 3, ko = (id & 7) * 8;
        *(uint4*)&As[row * 72 + ko] =
            *(const uint4*)(QKVb + (size_t)(r0 + row) * N3_ + h * DK_ + ko);
        *(uint4*)&Bs[row * 72 + ko] =
            *(const uint4*)(MtFS + ((size_t)bh * 128 + row) * 64 + ko);
    }
    if (t < 128) al[t] = alphaA[(size_t)bh * L_ + l0 + t];
    __syncthreads();
    {
        const int row = t >> 1, half = (t & 1) * 32;
        float s = 0.f;
        #pragma unroll
        for (int j = 0; j < 32; ++j) {
            const float v = bf2f(As[row * 72 + half + j]);
            s += v * v;
        }
        qs2[row][t & 1] = s;
    }
    const int wm = wv * 32;
    f32x4 acc[2][2][4] = {};
    #pragma unroll
    for (int kk = 0; kk < 2; ++kk) {
        bf16x8 af[2];
        #pragma unroll
        for (int m = 0; m < 2; ++m)
            af[m] = *(const bf16x8*)&As[(wm + m * 16 + ml) * 72 + kk * 32 + q * 8];
        #pragma unroll
        for (int s = 0; s < 2; ++s)
            #pragma unroll
            for (int n = 0; n < 4; ++n) {
                bf16x8 bf = *(const bf16x8*)&Bs[(s * 64 + n * 16 + ml) * 72 + kk * 32 + q * 8];
                #pragma unroll
                for (int m = 0; m < 2; ++m)
                    acc[s][m][n] = __builtin_amdgcn_mfma_f32_16x16x32_bf16(af[m], bf, acc[s][m][n], 0, 0, 0);
            }
    }
    __syncthreads();
    if (t < 128) nrm[t] = 1.f / fmaxf(sqrtf(qs2[t][0] + qs2[t][1]), 1e-12f);
    __syncthreads();
    unsigned short* Cs = Bs;
    #pragma unroll
    for (int m = 0; m < 2; ++m)
        #pragma unroll
        for (int r = 0; r < 4; ++r) {
            const int row = wm + m * 16 + q * 4 + r;
            const float a = al[row], sc = nrm[row];
            #pragma unroll
            for (int n = 0; n < 4; ++n) {
                const float v = sc * (a * acc[0][m][n][r] + (1.f - a) * acc[1][m][n][r]);
                Cs[row * 64 + n * 16 + ml] = f2bf(v);
            }
        }
    __syncthreads();
    const int row = t >> 1, eo = (t & 1) * 32;
    const uint4* src = (const uint4*)&Cs[row * 64 + eo];
    uint4* dst = (uint4*)(Ob + (size_t)(r0 + row) * D_ + h * DK_ + eo);
    #pragma unroll
    for (int u = 0; u < 4; ++u) dst[u] = src[u];
}

extern "C" void kernel_launch(void* const* d_in, const int* in_sizes, int n_in,
                              void* d_out, int out_size, void* d_ws, size_t ws_size,
                              hipStream_t stream)
{
    const float* x    = (const float*)d_in[0];
    const float* Wq   = (const float*)d_in[1];
    const float* Wk   = (const float*)d_in[2];
    const float* Wv   = (const float*)d_in[3];
    const float* Wb   = (const float*)d_in[4];
    const float* Wo   = (const float*)d_in[5];
    const float* Wfd  = (const float*)d_in[6];
    const float* bfd  = (const float*)d_in[7];
    const float* Wsd  = (const float*)d_in[8];
    const float* bsd  = (const float*)d_in[9];
    const float* Wtf1 = (const float*)d_in[10];
    const float* btf1 = (const float*)d_in[11];
    const float* Wtf2 = (const float*)d_in[12];
    const float* btf2 = (const float*)d_in[13];
    float* out        = (float*)d_out;

    char* w = (char*)d_ws;
    unsigned short* xb    = (unsigned short*)w; w += (size_t)R_ * D_ * 2;   // reused as Ob
    unsigned short* QKVb  = (unsigned short*)w; w += (size_t)R_ * N3_ * 2;
    unsigned short* Wtqkv = (unsigned short*)w; w += (size_t)3 * D_ * D_ * 2;
    unsigned short* Wto   = (unsigned short*)w; w += (size_t)D_ * D_ * 2;
    unsigned short* kfT   = (unsigned short*)w; w += (size_t)32 * DK_ * L_ * 2;
    unsigned short* ksT   = (unsigned short*)w; w += (size_t)32 * DK_ * L_ * 2;
    unsigned short* vT    = (unsigned short*)w; w += (size_t)32 * DK_ * L_ * 2;
    unsigned short* W3t   = (unsigned short*)w; w += (size_t)48 * D_ * 2;
    unsigned short* Wtf1t = (unsigned short*)w; w += (size_t)32 * DK_ * 2;
    unsigned short* MtFS  = (unsigned short*)w; w += (size_t)32 * 128 * DK_ * 2;
    float* beta   = (float*)w; w += 32 * L_ * 4;
    float* fastd  = (float*)w; w += 32 * L_ * 4;
    float* slowd  = (float*)w; w += 32 * L_ * 4;
    float* fw     = (float*)w; w += 32 * L_ * 4;
    float* sw     = (float*)w; w += 32 * L_ * 4;
    float* alphaA = (float*)w; w += 32 * L_ * 4;
    float* Mf     = (float*)w; w += 32 * DK_ * DK_ * 4;
    float* Ms     = (float*)w; w += 32 * DK_ * DK_ * 4;
    float* denom  = (float*)w; w += 64 * 4;

    prep_all_kernel<<<8192 + 4096 + 192 + 1, 256, 0, stream>>>(
        x, Wq, Wk, Wv, Wo, Wb, Wfd, Wsd, Wtf1, xb, Wtqkv, Wto, W3t, Wtf1t);

    proj_mfma_kernel<<<R_ / 64, 256, 0, stream>>>(xb, W3t, bfd, bsd, beta, fastd, slowd);
    scan_kernel<<<64, 256, 0, stream>>>(fastd, slowd, fw, sw, denom);

    gemm_bf16_kernel<true><<<dim3(N3_ / 128, R_ / 128), 256, 0, stream>>>(
        xb, Wtqkv, QKVb, R_, N3_, D_);

    ktv_flux_kernel<<<dim3(H_, B_, L_ / 64), 256, 0, stream>>>(
        QKVb, beta, fw, sw, Wtf1t, btf1, Wtf2, btf2, kfT, ksT, vT, alphaA);
    (void)hipMemsetAsync(Mf, 0, 2 * 32 * DK_ * DK_ * sizeof(float), stream);
    mstate_mfma_kernel<<<dim3(32, 16), 256, 0, stream>>>(kfT, ksT, vT, Mf, Ms);
    mprep_kernel<<<32, 256, 0, stream>>>(Mf, Ms, denom, MtFS);
    o_mfma_kernel<<<dim3(32, 32), 256, 0, stream>>>(QKVb, MtFS, alphaA, xb);
    gemm_bf16_kernel<false><<<dim3(D_ / 128, R_ / 128), 256, 0, stream>>>(
        xb, Wto, out, R_, D_, D_);
}